// Round 4
// baseline (227.860 us; speedup 1.0000x reference)
//
#include <hip/hip_runtime.h>

#define T_SEQ   2048
#define NHEADS  12
#define DHEAD   64
#define WIN     16
#define WW      32
#define NWIN    128
#define DMODEL  768
#define NABCDE  3840
#define IGNORE_V (-1.0e6f)
#define PAD_K   72          // bf16 LDS row stride for sc/sa/sb/sd/se
#define PM_P    40          // pm_s bf16 row stride
#define PL_P    36          // pl_s fp32 row stride

typedef float f32x4 __attribute__((ext_vector_type(4)));
typedef short bf16x8 __attribute__((ext_vector_type(8)));

__device__ __forceinline__ short f2bf(float f) {
    unsigned u = __float_as_uint(f);
    unsigned r = (u + 0x7FFF + ((u >> 16) & 1)) >> 16;   // RNE
    return (short)r;
}
__device__ __forceinline__ float bf2f(short s) {
    return __uint_as_float(((unsigned)(unsigned short)s) << 16);
}

__device__ __forceinline__ void gload_lds16(const short* g, short* l) {
    __builtin_amdgcn_global_load_lds(
        (const __attribute__((address_space(1))) void*)g,
        (__attribute__((address_space(3))) void*)l,
        16, 0, 0);
}

// elementwise bf16 product (truncating) via v_perm pack
__device__ __forceinline__ bf16x8 bmul8(bf16x8 x, bf16x8 y) {
    union { bf16x8 v; unsigned u[4]; } X, Y, R;
    X.v = x; Y.v = y;
#pragma unroll
    for (int j = 0; j < 4; ++j) {
        float xl = __uint_as_float(X.u[j] << 16);
        float xh = __uint_as_float(X.u[j] & 0xffff0000u);
        float yl = __uint_as_float(Y.u[j] << 16);
        float yh = __uint_as_float(Y.u[j] & 0xffff0000u);
        unsigned pl = __float_as_uint(xl * yl);
        unsigned ph = __float_as_uint(xh * yh);
        R.u[j] = __builtin_amdgcn_perm(ph, pl, 0x07060302);   // [hi16(ph):hi16(pl)]
    }
    return R.v;
}

// ---------------------------------------------------------------------------
__global__ __launch_bounds__(256) void cast_bf16_kernel(
    const float* __restrict__ in, short* __restrict__ out, int n)
{
    int i = (blockIdx.x * 256 + threadIdx.x) * 8;
    if (i >= n) return;
    float4 a = *reinterpret_cast<const float4*>(&in[i]);
    float4 b = *reinterpret_cast<const float4*>(&in[i + 4]);
    union { short s[8]; uint4 u; } r;
    r.s[0] = f2bf(a.x); r.s[1] = f2bf(a.y); r.s[2] = f2bf(a.z); r.s[3] = f2bf(a.w);
    r.s[4] = f2bf(b.x); r.s[5] = f2bf(b.y); r.s[6] = f2bf(b.z); r.s[7] = f2bf(b.w);
    *reinterpret_cast<uint4*>(&out[i]) = r.u;
}

__global__ __launch_bounds__(256) void transpose_cast_kernel(
    const float* __restrict__ W, short* __restrict__ Wt, int K, int N)
{
    __shared__ float tile[32][33];
    const int bx = blockIdx.x * 32;
    const int by = blockIdx.y * 32;
    const int tx = threadIdx.x & 31, ty = threadIdx.x >> 5;
#pragma unroll
    for (int r = 0; r < 32; r += 8)
        tile[ty + r][tx] = W[(size_t)(by + ty + r) * N + bx + tx];
    __syncthreads();
#pragma unroll
    for (int r = 0; r < 32; r += 8)
        Wt[(size_t)(bx + ty + r) * K + by + tx] = f2bf(tile[tx][ty + r]);
}

// ---------------------------------------------------------------------------
// bf16 MFMA GEMM 128x128: C = A @ Bt^T + bias. BF16OUT selects output type.
// ---------------------------------------------------------------------------
template <bool BF16OUT>
__global__ __launch_bounds__(256) void gemm_bf16_mfma(
    const short* __restrict__ A, const short* __restrict__ Bt,
    const float* __restrict__ bias, void* __restrict__ Cv,
    int M, int N, int K)
{
    __shared__ short As[128 * 32];
    __shared__ short Bs[128 * 32];

    const int tid  = threadIdx.x;
    const int wave = tid >> 6;
    const int lane = tid & 63;
    const int bm = blockIdx.y * 128;
    const int bn = blockIdx.x * 128;

    const int st_row = lane >> 2;
    const int st_col = (lane & 3) * 8;
    const int fr_m = lane & 15;
    const int fr_k = (lane >> 4) * 8;
    const int wm = (wave >> 1) * 64;
    const int wn = (wave & 1) * 64;

    f32x4 acc[4][4];
#pragma unroll
    for (int mi = 0; mi < 4; ++mi)
#pragma unroll
        for (int ni = 0; ni < 4; ++ni) acc[mi][ni] = (f32x4){0.f, 0.f, 0.f, 0.f};

    const short* Abase0 = A  + (size_t)(bm + wave * 32 + st_row)      * K + st_col;
    const short* Abase1 = A  + (size_t)(bm + wave * 32 + 16 + st_row) * K + st_col;
    const short* Bbase0 = Bt + (size_t)(bn + wave * 32 + st_row)      * K + st_col;
    const short* Bbase1 = Bt + (size_t)(bn + wave * 32 + 16 + st_row) * K + st_col;
    short* AL0 = &As[(wave * 32)      * 32];
    short* AL1 = &As[(wave * 32 + 16) * 32];
    short* BL0 = &Bs[(wave * 32)      * 32];
    short* BL1 = &Bs[(wave * 32 + 16) * 32];

    for (int k0 = 0; k0 < K; k0 += 32) {
        gload_lds16(Abase0 + k0, AL0);
        gload_lds16(Abase1 + k0, AL1);
        gload_lds16(Bbase0 + k0, BL0);
        gload_lds16(Bbase1 + k0, BL1);
        __syncthreads();

        bf16x8 af[4], bf[4];
#pragma unroll
        for (int mi = 0; mi < 4; ++mi)
            af[mi] = *reinterpret_cast<const bf16x8*>(
                &As[(wm + mi * 16 + fr_m) * 32 + fr_k]);
#pragma unroll
        for (int ni = 0; ni < 4; ++ni)
            bf[ni] = *reinterpret_cast<const bf16x8*>(
                &Bs[(wn + ni * 16 + fr_m) * 32 + fr_k]);
#pragma unroll
        for (int mi = 0; mi < 4; ++mi)
#pragma unroll
            for (int ni = 0; ni < 4; ++ni)
                acc[mi][ni] = __builtin_amdgcn_mfma_f32_16x16x32_bf16(
                    af[mi], bf[ni], acc[mi][ni], 0, 0, 0);
        __syncthreads();
    }

    float bv[4];
#pragma unroll
    for (int ni = 0; ni < 4; ++ni)
        bv[ni] = bias[bn + wn + ni * 16 + (lane & 15)];
#pragma unroll
    for (int mi = 0; mi < 4; ++mi) {
        int rbase = bm + wm + mi * 16 + (lane >> 4) * 4;
#pragma unroll
        for (int r = 0; r < 4; ++r) {
            size_t off = (size_t)(rbase + r) * N + bn + wn + (lane & 15);
#pragma unroll
            for (int ni = 0; ni < 4; ++ni) {
                float val = acc[mi][ni][r] + bv[ni];
                if (BF16OUT) ((short*)Cv)[off + ni * 16] = f2bf(val);
                else         ((float*)Cv)[off + ni * 16] = val;
            }
        }
    }
}

// ---------------------------------------------------------------------------
// bf16 MFMA GEMM 128x64 tile (for N=768: 384 blocks instead of 192).
// Waves arranged 4x1 over M; fp32 output.
// ---------------------------------------------------------------------------
__global__ __launch_bounds__(256) void gemm_bf16_mfma_n64(
    const short* __restrict__ A, const short* __restrict__ Bt,
    const float* __restrict__ bias, float* __restrict__ C,
    int M, int N, int K)
{
    __shared__ short As[128 * 32];
    __shared__ short Bs[64 * 32];

    const int tid  = threadIdx.x;
    const int wave = tid >> 6;
    const int lane = tid & 63;
    const int bm = blockIdx.y * 128;
    const int bn = blockIdx.x * 64;

    const int st_row = lane >> 2;
    const int st_col = (lane & 3) * 8;
    const int fr_m = lane & 15;
    const int fr_k = (lane >> 4) * 8;
    const int wm = wave * 32;
    const bool doB = (wave < 2);

    f32x4 acc[2][4];
#pragma unroll
    for (int mi = 0; mi < 2; ++mi)
#pragma unroll
        for (int ni = 0; ni < 4; ++ni) acc[mi][ni] = (f32x4){0.f, 0.f, 0.f, 0.f};

    const short* Abase0 = A  + (size_t)(bm + wm + st_row)      * K + st_col;
    const short* Abase1 = A  + (size_t)(bm + wm + 16 + st_row) * K + st_col;
    const short* Bbase0 = Bt + (size_t)(bn + (wave & 1) * 32 + st_row)      * K + st_col;
    const short* Bbase1 = Bt + (size_t)(bn + (wave & 1) * 32 + 16 + st_row) * K + st_col;
    short* AL0 = &As[(wm)      * 32];
    short* AL1 = &As[(wm + 16) * 32];
    short* BL0 = &Bs[((wave & 1) * 32)      * 32];
    short* BL1 = &Bs[((wave & 1) * 32 + 16) * 32];

    for (int k0 = 0; k0 < K; k0 += 32) {
        gload_lds16(Abase0 + k0, AL0);
        gload_lds16(Abase1 + k0, AL1);
        if (doB) {
            gload_lds16(Bbase0 + k0, BL0);
            gload_lds16(Bbase1 + k0, BL1);
        }
        __syncthreads();

        bf16x8 af[2], bf[4];
#pragma unroll
        for (int mi = 0; mi < 2; ++mi)
            af[mi] = *reinterpret_cast<const bf16x8*>(
                &As[(wm + mi * 16 + fr_m) * 32 + fr_k]);
#pragma unroll
        for (int ni = 0; ni < 4; ++ni)
            bf[ni] = *reinterpret_cast<const bf16x8*>(
                &Bs[(ni * 16 + fr_m) * 32 + fr_k]);
#pragma unroll
        for (int mi = 0; mi < 2; ++mi)
#pragma unroll
            for (int ni = 0; ni < 4; ++ni)
                acc[mi][ni] = __builtin_amdgcn_mfma_f32_16x16x32_bf16(
                    af[mi], bf[ni], acc[mi][ni], 0, 0, 0);
        __syncthreads();
    }

    float bv[4];
#pragma unroll
    for (int ni = 0; ni < 4; ++ni)
        bv[ni] = bias[bn + ni * 16 + (lane & 15)];
#pragma unroll
    for (int mi = 0; mi < 2; ++mi) {
        int rbase = bm + wm + mi * 16 + (lane >> 4) * 4;
#pragma unroll
        for (int r = 0; r < 4; ++r) {
            size_t off = (size_t)(rbase + r) * N + bn + (lane & 15);
#pragma unroll
            for (int ni = 0; ni < 4; ++ni)
                C[off + ni * 16] = acc[mi][ni][r] + bv[ni];
        }
    }
}

// ---------------------------------------------------------------------------
// Windowed trittention, MFMA scores + MFMA epilogue.
// Score C-layout per wave: i = ko*4+reg, l = h2*16+lc; m = wv*8+mi in regs.
// ---------------------------------------------------------------------------
__global__ __launch_bounds__(256) void attn_kernel(
    const short* __restrict__ abcde, short* __restrict__ z)
{
    const int blk = blockIdx.x;
    const int n  = blk & (NWIN - 1);
    const int bh = blk >> 7;
    const int b  = bh / NHEADS;
    const int h  = bh % NHEADS;

    __shared__ short sc[WIN * PAD_K];
    __shared__ short sa[WW * PAD_K];
    __shared__ short sb[WW * PAD_K];
    __shared__ short sd[WW * PAD_K];
    __shared__ short se[WW * PAD_K];
    __shared__ short pm_s[WIN * PM_P];     // bf16, unnormalized row-marginal
    __shared__ float pl_s[WIN * PL_P];     // fp32, ds_add accumulated col-marginal
    __shared__ float red0[WIN][4];         // per-wave max partials
    __shared__ float red1[WIN][4];         // per-wave sum partials

    const int tid = threadIdx.x;
    const size_t rowbase = ((size_t)b * T_SEQ) * NABCDE;
    const int hd = h * DHEAD;

    // ---- staging + pl zero-init
    if (tid < 128) {
        int row = tid >> 3, ch = (tid & 7) * 8;
        *reinterpret_cast<uint4*>(&sc[row * PAD_K + ch]) =
            *reinterpret_cast<const uint4*>(
                &abcde[rowbase + (size_t)(n * WIN + row) * NABCDE + 2 * DMODEL + hd + ch]);
    }
    {
        int row = tid >> 3, ch = (tid & 7) * 8;
        int t = n * WIN - WIN + row;
        uint4 va = {0u, 0u, 0u, 0u}, vb = va, vd = va, ve = va;
        if (t >= 0) {
            size_t base = rowbase + (size_t)t * NABCDE + hd + ch;
            va = *reinterpret_cast<const uint4*>(&abcde[base + 0 * DMODEL]);
            vb = *reinterpret_cast<const uint4*>(&abcde[base + 1 * DMODEL]);
            vd = *reinterpret_cast<const uint4*>(&abcde[base + 3 * DMODEL]);
            ve = *reinterpret_cast<const uint4*>(&abcde[base + 4 * DMODEL]);
        }
        *reinterpret_cast<uint4*>(&sa[row * PAD_K + ch]) = va;
        *reinterpret_cast<uint4*>(&sb[row * PAD_K + ch]) = vb;
        *reinterpret_cast<uint4*>(&sd[row * PAD_K + ch]) = vd;
        *reinterpret_cast<uint4*>(&se[row * PAD_K + ch]) = ve;
    }
#pragma unroll
    for (int q = tid; q < WIN * PL_P; q += 256) pl_s[q] = 0.f;
    __syncthreads();   // B1

    const int wv = tid >> 6;
    const int lane = tid & 63;
    const int lc = lane & 15;
    const int ko = lane >> 4;

    // ---- score fragments
    bf16x8 cfrag[2], bfrag[2][2];
#pragma unroll
    for (int kt = 0; kt < 2; ++kt) {
        cfrag[kt]    = *reinterpret_cast<const bf16x8*>(&sc[lc * PAD_K + kt * 32 + ko * 8]);
        bfrag[0][kt] = *reinterpret_cast<const bf16x8*>(&sb[lc * PAD_K + kt * 32 + ko * 8]);
        bfrag[1][kt] = *reinterpret_cast<const bf16x8*>(&sb[(16 + lc) * PAD_K + kt * 32 + ko * 8]);
    }

    f32x4 acc[8][2];
#pragma unroll
    for (int mi = 0; mi < 8; ++mi) {
        acc[mi][0] = (f32x4){0.f, 0.f, 0.f, 0.f};
        acc[mi][1] = (f32x4){0.f, 0.f, 0.f, 0.f};
    }
#pragma unroll
    for (int mi = 0; mi < 8; ++mi) {
        int m = wv * 8 + mi;
#pragma unroll
        for (int kt = 0; kt < 2; ++kt) {
            bf16x8 ar = *reinterpret_cast<const bf16x8*>(&sa[m * PAD_K + kt * 32 + ko * 8]);
            bf16x8 af = bmul8(cfrag[kt], ar);
            acc[mi][0] = __builtin_amdgcn_mfma_f32_16x16x32_bf16(af, bfrag[0][kt], acc[mi][0], 0, 0, 0);
            acc[mi][1] = __builtin_amdgcn_mfma_f32_16x16x32_bf16(af, bfrag[1][kt], acc[mi][1], 0, 0, 0);
        }
    }

    // ---- mask (raw scores) + per-lane max
    const int nbase = n * WIN;
    int bbl_h[2];
    bool keepL[2][4];
#pragma unroll
    for (int h2 = 0; h2 < 2; ++h2) {
        int l = h2 * 16 + lc;
        bbl_h[h2] = (n == 0 && l < WIN) ? 0 : (nbase - WIN + l);
#pragma unroll
        for (int reg = 0; reg < 4; ++reg)
            keepL[h2][reg] = (nbase + ko * 4 + reg) >= bbl_h[h2];
    }
    float mx[4] = {-3.4e38f, -3.4e38f, -3.4e38f, -3.4e38f};
#pragma unroll
    for (int mi = 0; mi < 8; ++mi) {
        int m = wv * 8 + mi;
        int bbm = (n == 0 && m < WIN) ? 0 : (nbase - WIN + m);
#pragma unroll
        for (int h2 = 0; h2 < 2; ++h2) {
            bool mgt = bbl_h[h2] > bbm;
#pragma unroll
            for (int reg = 0; reg < 4; ++reg) {
                float v = acc[mi][h2][reg];
                bool keep = keepL[h2][reg] && mgt;
                if (!keep || v == 0.0f) v = IGNORE_V;
                acc[mi][h2][reg] = v;
                mx[reg] = fmaxf(mx[reg], v);
            }
        }
    }
#pragma unroll
    for (int reg = 0; reg < 4; ++reg) {
        mx[reg] = fmaxf(mx[reg], __shfl_xor(mx[reg], 1, 64));
        mx[reg] = fmaxf(mx[reg], __shfl_xor(mx[reg], 2, 64));
        mx[reg] = fmaxf(mx[reg], __shfl_xor(mx[reg], 4, 64));
        mx[reg] = fmaxf(mx[reg], __shfl_xor(mx[reg], 8, 64));
    }
    if (lc == 0) {
#pragma unroll
        for (int reg = 0; reg < 4; ++reg) red0[ko * 4 + reg][wv] = mx[reg];
    }
    __syncthreads();   // B2

    float gm64[4];
#pragma unroll
    for (int reg = 0; reg < 4; ++reg) {
        f32x4 r0 = *reinterpret_cast<const f32x4*>(&red0[ko * 4 + reg][0]);
        float g = fmaxf(fmaxf(r0[0], r0[1]), fmaxf(r0[2], r0[3]));
        gm64[reg] = g * 0.015625f;   // gmax/64
    }

    // ---- exp((v - gmax)/64) + per-lane sum
    float sm[4] = {0.f, 0.f, 0.f, 0.f};
#pragma unroll
    for (int mi = 0; mi < 8; ++mi)
#pragma unroll
        for (int h2 = 0; h2 < 2; ++h2)
#pragma unroll
            for (int reg = 0; reg < 4; ++reg) {
                float e = __expf(fmaf(acc[mi][h2][reg], 0.015625f, -gm64[reg]));
                acc[mi][h2][reg] = e;
                sm[reg] += e;
            }
#pragma unroll
    for (int reg = 0; reg < 4; ++reg) {
        sm[reg] += __shfl_xor(sm[reg], 1, 64);
        sm[reg] += __shfl_xor(sm[reg], 2, 64);
        sm[reg] += __shfl_xor(sm[reg], 4, 64);
        sm[reg] += __shfl_xor(sm[reg], 8, 64);
    }
    if (lc == 0) {
#pragma unroll
        for (int reg = 0; reg < 4; ++reg) red1[ko * 4 + reg][wv] = sm[reg];
    }

    // ---- marginals (unnormalized)
    // pl[i][l] += sum_mi via ds_add_f32
#pragma unroll
    for (int h2 = 0; h2 < 2; ++h2)
#pragma unroll
        for (int reg = 0; reg < 4; ++reg) {
            float pl = 0.f;
#pragma unroll
            for (int mi = 0; mi < 8; ++mi) pl += acc[mi][h2][reg];
            atomicAdd(&pl_s[(ko * 4 + reg) * PL_P + h2 * 16 + lc], pl);
        }
    // pm[i][m]: butterfly over lc, lane lc==mi writes bf16
#pragma unroll
    for (int mi = 0; mi < 8; ++mi) {
        float pmv[4];
#pragma unroll
        for (int reg = 0; reg < 4; ++reg) {
            float pm = acc[mi][0][reg] + acc[mi][1][reg];
            pm += __shfl_xor(pm, 1, 64);
            pm += __shfl_xor(pm, 2, 64);
            pm += __shfl_xor(pm, 4, 64);
            pm += __shfl_xor(pm, 8, 64);
            pmv[reg] = pm;
        }
        if (lc == mi) {
#pragma unroll
            for (int reg = 0; reg < 4; ++reg)
                pm_s[(ko * 4 + reg) * PM_P + wv * 8 + mi] = f2bf(pmv[reg]);
        }
    }
    __syncthreads();   // B3

    // ---- inverse denominators (per i = ko*4+reg)
    float inv[4];
#pragma unroll
    for (int reg = 0; reg < 4; ++reg) {
        f32x4 r1 = *reinterpret_cast<const f32x4*>(&red1[ko * 4 + reg][0]);
        inv[reg] = 1.0f / (r1[0] + r1[1] + r1[2] + r1[3]);
    }

    // ---- epilogue MFMA: z[i][dd] = pm @ d + pl @ e, wave wv owns dd-tile wv
    // A-frag kt=0: pm_s row lc (bf16 direct); kt=1: pl_s row lc (fp32 -> bf16)
    bf16x8 apm = *reinterpret_cast<const bf16x8*>(&pm_s[lc * PM_P + ko * 8]);
    bf16x8 apl;
    {
        f32x4 p0 = *reinterpret_cast<const f32x4*>(&pl_s[lc * PL_P + ko * 8]);
        f32x4 p1 = *reinterpret_cast<const f32x4*>(&pl_s[lc * PL_P + ko * 8 + 4]);
        union { short s[8]; bf16x8 v; } t;
#pragma unroll
        for (int j = 0; j < 4; ++j) { t.s[j] = f2bf(p0[j]); t.s[4 + j] = f2bf(p1[j]); }
        apl = t.v;
    }
    // B-frags: B[dd][k] = d[k][dd] (kt=0) / e[k][dd] (kt=1), strided u16 reads
    // with ko-rotated order for conflict-freedom.
    const int dd = wv * 16 + lc;
    bf16x8 bd, be;
    {
        unsigned dv[8], ev[8];
#pragma unroll
        for (int r = 0; r < 8; ++r) {
            int j = (r + 2 * ko) & 7;
            dv[j] = *reinterpret_cast<const unsigned short*>(&sd[(ko * 8 + j) * PAD_K + dd]);
            ev[j] = *reinterpret_cast<const unsigned short*>(&se[(ko * 8 + j) * PAD_K + dd]);
        }
        union { unsigned u[4]; bf16x8 v; } td, te;
#pragma unroll
        for (int j = 0; j < 4; ++j) {
            td.u[j] = __builtin_amdgcn_perm(dv[2 * j + 1], dv[2 * j], 0x05040100);
            te.u[j] = __builtin_amdgcn_perm(ev[2 * j + 1], ev[2 * j], 0x05040100);
        }
        bd = td.v; be = te.v;
    }
    f32x4 zacc = (f32x4){0.f, 0.f, 0.f, 0.f};
    zacc = __builtin_amdgcn_mfma_f32_16x16x32_bf16(apm, bd, zacc, 0, 0, 0);
    zacc = __builtin_amdgcn_mfma_f32_16x16x32_bf16(apl, be, zacc, 0, 0, 0);

#pragma unroll
    for (int reg = 0; reg < 4; ++reg) {
        int t = nbase + ko * 4 + reg;
        z[((size_t)b * T_SEQ + t) * (NHEADS * DHEAD) + hd + dd] = f2bf(zacc[reg] * inv[reg]);
    }
}

// ---------------------------------------------------------------------------
extern "C" void kernel_launch(void* const* d_in, const int* in_sizes, int n_in,
                              void* d_out, int out_size, void* d_ws, size_t ws_size,
                              hipStream_t stream) {
    const float* x        = (const float*)d_in[0];
    const float* W_abcde  = (const float*)d_in[1];
    const float* b_abcde  = (const float*)d_in[2];
    const float* W_O      = (const float*)d_in[3];
    const float* b_O      = (const float*)d_in[4];
    float* out = (float*)d_out;

    char* ws = (char*)d_ws;
    short* abcde = (short*)ws;                                 // 4096x3840 bf16
    short* xb    = (short*)(ws + (size_t)31457280);            // 4096x768 bf16, reused as zb
    short* Wt    = (short*)(ws + (size_t)31457280 + 6291456);  // 3840x768 bf16, reused as WOt
    short* zb    = xb;
    short* WOt   = Wt;

    const int M = 2 * T_SEQ;  // 4096

    cast_bf16_kernel<<<dim3((M * DMODEL / 8 + 255) / 256), dim3(256), 0, stream>>>(
        x, xb, M * DMODEL);
    transpose_cast_kernel<<<dim3(NABCDE / 32, DMODEL / 32), dim3(256), 0, stream>>>(
        W_abcde, Wt, DMODEL, NABCDE);

    gemm_bf16_mfma<true><<<dim3(NABCDE / 128, M / 128), dim3(256), 0, stream>>>(
        xb, Wt, b_abcde, (void*)abcde, M, NABCDE, DMODEL);

    attn_kernel<<<dim3(2 * NHEADS * NWIN), dim3(256), 0, stream>>>(abcde, zb);

    transpose_cast_kernel<<<dim3(DMODEL / 32, DMODEL / 32), dim3(256), 0, stream>>>(
        W_O, WOt, DMODEL, DMODEL);

    gemm_bf16_mfma_n64<<<dim3(DMODEL / 64, M / 128), dim3(256), 0, stream>>>(
        zb, WOt, b_O, out, M, DMODEL, DMODEL);
}

// Round 5
// 196.895 us; speedup vs baseline: 1.1573x; 1.1573x over previous
//
#include <hip/hip_runtime.h>

#define T_SEQ   2048
#define NHEADS  12
#define DHEAD   64
#define WIN     16
#define WW      32
#define NWIN    128
#define DMODEL  768
#define NABCDE  3840
#define IGNORE_V (-1.0e6f)
#define PAD_K   72          // bf16 LDS row stride (144 B, 16B-aligned)
#define L2E64   0.022542110013890053f   // log2(e)/64

typedef float f32x4 __attribute__((ext_vector_type(4)));
typedef short bf16x8 __attribute__((ext_vector_type(8)));

__device__ __forceinline__ short f2bf(float f) {
    unsigned u = __float_as_uint(f);
    unsigned r = (u + 0x7FFF + ((u >> 16) & 1)) >> 16;   // RNE
    return (short)r;
}
__device__ __forceinline__ float bf2f(short s) {
    return __uint_as_float(((unsigned)(unsigned short)s) << 16);
}

__device__ __forceinline__ void gload_lds16(const short* g, short* l) {
    __builtin_amdgcn_global_load_lds(
        (const __attribute__((address_space(1))) void*)g,
        (__attribute__((address_space(3))) void*)l,
        16, 0, 0);
}

// elementwise bf16 product (truncating) via v_perm pack
__device__ __forceinline__ bf16x8 bmul8(bf16x8 x, bf16x8 y) {
    union { bf16x8 v; unsigned u[4]; } X, Y, R;
    X.v = x; Y.v = y;
#pragma unroll
    for (int j = 0; j < 4; ++j) {
        float xl = __uint_as_float(X.u[j] << 16);
        float xh = __uint_as_float(X.u[j] & 0xffff0000u);
        float yl = __uint_as_float(Y.u[j] << 16);
        float yh = __uint_as_float(Y.u[j] & 0xffff0000u);
        unsigned pl = __float_as_uint(xl * yl);
        unsigned ph = __float_as_uint(xh * yh);
        R.u[j] = __builtin_amdgcn_perm(ph, pl, 0x07060302);
    }
    return R.v;
}

// ---------------------------------------------------------------------------
__global__ __launch_bounds__(256) void cast_bf16_kernel(
    const float* __restrict__ in, short* __restrict__ out, int n)
{
    int i = (blockIdx.x * 256 + threadIdx.x) * 8;
    if (i >= n) return;
    float4 a = *reinterpret_cast<const float4*>(&in[i]);
    float4 b = *reinterpret_cast<const float4*>(&in[i + 4]);
    union { short s[8]; uint4 u; } r;
    r.s[0] = f2bf(a.x); r.s[1] = f2bf(a.y); r.s[2] = f2bf(a.z); r.s[3] = f2bf(a.w);
    r.s[4] = f2bf(b.x); r.s[5] = f2bf(b.y); r.s[6] = f2bf(b.z); r.s[7] = f2bf(b.w);
    *reinterpret_cast<uint4*>(&out[i]) = r.u;
}

__global__ __launch_bounds__(256) void transpose_cast_kernel(
    const float* __restrict__ W, short* __restrict__ Wt, int K, int N)
{
    __shared__ float tile[32][33];
    const int bx = blockIdx.x * 32;
    const int by = blockIdx.y * 32;
    const int tx = threadIdx.x & 31, ty = threadIdx.x >> 5;
#pragma unroll
    for (int r = 0; r < 32; r += 8)
        tile[ty + r][tx] = W[(size_t)(by + ty + r) * N + bx + tx];
    __syncthreads();
#pragma unroll
    for (int r = 0; r < 32; r += 8)
        Wt[(size_t)(bx + ty + r) * K + by + tx] = f2bf(tile[tx][ty + r]);
}

// ---------------------------------------------------------------------------
// bf16 MFMA GEMM 128x128: C = A @ Bt^T + bias. BF16OUT selects output type.
// ---------------------------------------------------------------------------
template <bool BF16OUT>
__global__ __launch_bounds__(256) void gemm_bf16_mfma(
    const short* __restrict__ A, const short* __restrict__ Bt,
    const float* __restrict__ bias, void* __restrict__ Cv,
    int M, int N, int K)
{
    __shared__ short As[128 * 32];
    __shared__ short Bs[128 * 32];

    const int tid  = threadIdx.x;
    const int wave = tid >> 6;
    const int lane = tid & 63;
    const int bm = blockIdx.y * 128;
    const int bn = blockIdx.x * 128;

    const int st_row = lane >> 2;
    const int st_col = (lane & 3) * 8;
    const int fr_m = lane & 15;
    const int fr_k = (lane >> 4) * 8;
    const int wm = (wave >> 1) * 64;
    const int wn = (wave & 1) * 64;

    f32x4 acc[4][4];
#pragma unroll
    for (int mi = 0; mi < 4; ++mi)
#pragma unroll
        for (int ni = 0; ni < 4; ++ni) acc[mi][ni] = (f32x4){0.f, 0.f, 0.f, 0.f};

    const short* Abase0 = A  + (size_t)(bm + wave * 32 + st_row)      * K + st_col;
    const short* Abase1 = A  + (size_t)(bm + wave * 32 + 16 + st_row) * K + st_col;
    const short* Bbase0 = Bt + (size_t)(bn + wave * 32 + st_row)      * K + st_col;
    const short* Bbase1 = Bt + (size_t)(bn + wave * 32 + 16 + st_row) * K + st_col;
    short* AL0 = &As[(wave * 32)      * 32];
    short* AL1 = &As[(wave * 32 + 16) * 32];
    short* BL0 = &Bs[(wave * 32)      * 32];
    short* BL1 = &Bs[(wave * 32 + 16) * 32];

    for (int k0 = 0; k0 < K; k0 += 32) {
        gload_lds16(Abase0 + k0, AL0);
        gload_lds16(Abase1 + k0, AL1);
        gload_lds16(Bbase0 + k0, BL0);
        gload_lds16(Bbase1 + k0, BL1);
        __syncthreads();

        bf16x8 af[4], bf[4];
#pragma unroll
        for (int mi = 0; mi < 4; ++mi)
            af[mi] = *reinterpret_cast<const bf16x8*>(
                &As[(wm + mi * 16 + fr_m) * 32 + fr_k]);
#pragma unroll
        for (int ni = 0; ni < 4; ++ni)
            bf[ni] = *reinterpret_cast<const bf16x8*>(
                &Bs[(wn + ni * 16 + fr_m) * 32 + fr_k]);
#pragma unroll
        for (int mi = 0; mi < 4; ++mi)
#pragma unroll
            for (int ni = 0; ni < 4; ++ni)
                acc[mi][ni] = __builtin_amdgcn_mfma_f32_16x16x32_bf16(
                    af[mi], bf[ni], acc[mi][ni], 0, 0, 0);
        __syncthreads();
    }

    float bv[4];
#pragma unroll
    for (int ni = 0; ni < 4; ++ni)
        bv[ni] = bias[bn + wn + ni * 16 + (lane & 15)];
#pragma unroll
    for (int mi = 0; mi < 4; ++mi) {
        int rbase = bm + wm + mi * 16 + (lane >> 4) * 4;
#pragma unroll
        for (int r = 0; r < 4; ++r) {
            size_t off = (size_t)(rbase + r) * N + bn + wn + (lane & 15);
#pragma unroll
            for (int ni = 0; ni < 4; ++ni) {
                float val = acc[mi][ni][r] + bv[ni];
                if (BF16OUT) ((short*)Cv)[off + ni * 16] = f2bf(val);
                else         ((float*)Cv)[off + ni * 16] = val;
            }
        }
    }
}

// ---------------------------------------------------------------------------
// bf16 MFMA GEMM 128x64 tile (N=768 -> 384 blocks), fp32 out.
// ---------------------------------------------------------------------------
__global__ __launch_bounds__(256) void gemm_bf16_mfma_n64(
    const short* __restrict__ A, const short* __restrict__ Bt,
    const float* __restrict__ bias, float* __restrict__ C,
    int M, int N, int K)
{
    __shared__ short As[128 * 32];
    __shared__ short Bs[64 * 32];

    const int tid  = threadIdx.x;
    const int wave = tid >> 6;
    const int lane = tid & 63;
    const int bm = blockIdx.y * 128;
    const int bn = blockIdx.x * 64;

    const int st_row = lane >> 2;
    const int st_col = (lane & 3) * 8;
    const int fr_m = lane & 15;
    const int fr_k = (lane >> 4) * 8;
    const int wm = wave * 32;
    const bool doB = (wave < 2);

    f32x4 acc[2][4];
#pragma unroll
    for (int mi = 0; mi < 2; ++mi)
#pragma unroll
        for (int ni = 0; ni < 4; ++ni) acc[mi][ni] = (f32x4){0.f, 0.f, 0.f, 0.f};

    const short* Abase0 = A  + (size_t)(bm + wm + st_row)      * K + st_col;
    const short* Abase1 = A  + (size_t)(bm + wm + 16 + st_row) * K + st_col;
    const short* Bbase0 = Bt + (size_t)(bn + (wave & 1) * 32 + st_row)      * K + st_col;
    const short* Bbase1 = Bt + (size_t)(bn + (wave & 1) * 32 + 16 + st_row) * K + st_col;
    short* AL0 = &As[(wm)      * 32];
    short* AL1 = &As[(wm + 16) * 32];
    short* BL0 = &Bs[((wave & 1) * 32)      * 32];
    short* BL1 = &Bs[((wave & 1) * 32 + 16) * 32];

    for (int k0 = 0; k0 < K; k0 += 32) {
        gload_lds16(Abase0 + k0, AL0);
        gload_lds16(Abase1 + k0, AL1);
        if (doB) {
            gload_lds16(Bbase0 + k0, BL0);
            gload_lds16(Bbase1 + k0, BL1);
        }
        __syncthreads();

        bf16x8 af[2], bf[4];
#pragma unroll
        for (int mi = 0; mi < 2; ++mi)
            af[mi] = *reinterpret_cast<const bf16x8*>(
                &As[(wm + mi * 16 + fr_m) * 32 + fr_k]);
#pragma unroll
        for (int ni = 0; ni < 4; ++ni)
            bf[ni] = *reinterpret_cast<const bf16x8*>(
                &Bs[(ni * 16 + fr_m) * 32 + fr_k]);
#pragma unroll
        for (int mi = 0; mi < 2; ++mi)
#pragma unroll
            for (int ni = 0; ni < 4; ++ni)
                acc[mi][ni] = __builtin_amdgcn_mfma_f32_16x16x32_bf16(
                    af[mi], bf[ni], acc[mi][ni], 0, 0, 0);
        __syncthreads();
    }

    float bv[4];
#pragma unroll
    for (int ni = 0; ni < 4; ++ni)
        bv[ni] = bias[bn + ni * 16 + (lane & 15)];
#pragma unroll
    for (int mi = 0; mi < 2; ++mi) {
        int rbase = bm + wm + mi * 16 + (lane >> 4) * 4;
#pragma unroll
        for (int r = 0; r < 4; ++r) {
            size_t off = (size_t)(rbase + r) * N + bn + (lane & 15);
#pragma unroll
            for (int ni = 0; ni < 4; ++ni)
                C[off + ni * 16] = acc[mi][ni][r] + bv[ni];
        }
    }
}

// ---------------------------------------------------------------------------
// Windowed trittention, wave-private softmax.
// Score MFMA rows = m_local*4 + i_local: wave wv owns queries wv*4..wv*4+3
// and computes ALL (m,l) for them. 8 row-tiles (mt) x 2 l-tiles x 2 k-tiles
// = 32 MFMAs/wave. C-layout gives i_local = reg, m_local = ko, l = lt*16+lc.
// Softmax/marginals fully intra-wave; ONE barrier (B2) shares [pm|pl] rows
// for the cooperative epilogue MFMA.
// ---------------------------------------------------------------------------
__global__ __launch_bounds__(256) void attn_kernel(
    const short* __restrict__ abcde, short* __restrict__ z)
{
    const int blk = blockIdx.x;
    const int n  = blk & (NWIN - 1);
    const int bh = blk >> 7;
    const int b  = bh / NHEADS;
    const int h  = bh % NHEADS;

    __shared__ short sc[WIN * PAD_K];
    __shared__ short sa[WW * PAD_K];
    __shared__ short sb[WW * PAD_K];
    __shared__ short sd[WW * PAD_K];
    __shared__ short se[WW * PAD_K];
    __shared__ short epA[WIN * PAD_K];     // [i][0..31]=pm, [32..63]=pl (bf16, unnorm)
    __shared__ float sinv[WIN];            // 1/denominator per query

    const int tid = threadIdx.x;
    const size_t rowbase = ((size_t)b * T_SEQ) * NABCDE;
    const int hd = h * DHEAD;

    // ---- staging
    if (tid < 128) {
        int row = tid >> 3, ch = (tid & 7) * 8;
        *reinterpret_cast<uint4*>(&sc[row * PAD_K + ch]) =
            *reinterpret_cast<const uint4*>(
                &abcde[rowbase + (size_t)(n * WIN + row) * NABCDE + 2 * DMODEL + hd + ch]);
    }
    {
        int row = tid >> 3, ch = (tid & 7) * 8;
        int t = n * WIN - WIN + row;
        uint4 va = {0u, 0u, 0u, 0u}, vb = va, vd = va, ve = va;
        if (t >= 0) {
            size_t base = rowbase + (size_t)t * NABCDE + hd + ch;
            va = *reinterpret_cast<const uint4*>(&abcde[base + 0 * DMODEL]);
            vb = *reinterpret_cast<const uint4*>(&abcde[base + 1 * DMODEL]);
            vd = *reinterpret_cast<const uint4*>(&abcde[base + 3 * DMODEL]);
            ve = *reinterpret_cast<const uint4*>(&abcde[base + 4 * DMODEL]);
        }
        *reinterpret_cast<uint4*>(&sa[row * PAD_K + ch]) = va;
        *reinterpret_cast<uint4*>(&sb[row * PAD_K + ch]) = vb;
        *reinterpret_cast<uint4*>(&sd[row * PAD_K + ch]) = vd;
        *reinterpret_cast<uint4*>(&se[row * PAD_K + ch]) = ve;
    }
    __syncthreads();   // B1

    const int wv = tid >> 6;
    const int lane = tid & 63;
    const int lc = lane & 15;
    const int ko = lane >> 4;

    // ---- fragments: cfrag for this lane's query (wv*4 + (lc&3));
    //      a-row for m_local = lc>>2; bfrag for l = lt*16+lc.
    bf16x8 cfrag[2], bfrag[2][2];
#pragma unroll
    for (int kt = 0; kt < 2; ++kt) {
        cfrag[kt]    = *reinterpret_cast<const bf16x8*>(
            &sc[(wv * 4 + (lc & 3)) * PAD_K + kt * 32 + ko * 8]);
        bfrag[0][kt] = *reinterpret_cast<const bf16x8*>(&sb[lc * PAD_K + kt * 32 + ko * 8]);
        bfrag[1][kt] = *reinterpret_cast<const bf16x8*>(&sb[(16 + lc) * PAD_K + kt * 32 + ko * 8]);
    }

    f32x4 acc[8][2];
#pragma unroll
    for (int mt = 0; mt < 8; ++mt) {
        acc[mt][0] = (f32x4){0.f, 0.f, 0.f, 0.f};
        acc[mt][1] = (f32x4){0.f, 0.f, 0.f, 0.f};
    }
#pragma unroll
    for (int mt = 0; mt < 8; ++mt) {
#pragma unroll
        for (int kt = 0; kt < 2; ++kt) {
            bf16x8 ar = *reinterpret_cast<const bf16x8*>(
                &sa[(mt * 4 + (lc >> 2)) * PAD_K + kt * 32 + ko * 8]);
            bf16x8 af = bmul8(cfrag[kt], ar);
            acc[mt][0] = __builtin_amdgcn_mfma_f32_16x16x32_bf16(af, bfrag[0][kt], acc[mt][0], 0, 0, 0);
            acc[mt][1] = __builtin_amdgcn_mfma_f32_16x16x32_bf16(af, bfrag[1][kt], acc[mt][1], 0, 0, 0);
        }
    }

    // ---- mask + per-query max (queries i = wv*4+reg, m = mt*4+ko, l = lt*16+lc)
    const int nbase = n * WIN;
    int bbl_h[2];
#pragma unroll
    for (int lt = 0; lt < 2; ++lt) {
        int l = lt * 16 + lc;
        bbl_h[lt] = (n == 0 && l < WIN) ? 0 : (nbase - WIN + l);
    }
    float mx[4] = {-3.4e38f, -3.4e38f, -3.4e38f, -3.4e38f};
#pragma unroll
    for (int mt = 0; mt < 8; ++mt) {
        int m = mt * 4 + ko;
        int bbm = (n == 0 && m < WIN) ? 0 : (nbase - WIN + m);
#pragma unroll
        for (int lt = 0; lt < 2; ++lt) {
            bool mgt = bbl_h[lt] > bbm;
#pragma unroll
            for (int reg = 0; reg < 4; ++reg) {
                int tq = nbase + wv * 4 + reg;
                float v = acc[mt][lt][reg];
                bool keep = (tq >= bbl_h[lt]) && mgt;
                if (!keep || v == 0.0f) v = IGNORE_V;
                acc[mt][lt][reg] = v;
                mx[reg] = fmaxf(mx[reg], v);
            }
        }
    }
#pragma unroll
    for (int reg = 0; reg < 4; ++reg) {
#pragma unroll
        for (int off = 1; off < 64; off <<= 1)
            mx[reg] = fmaxf(mx[reg], __shfl_xor(mx[reg], off, 64));
    }

    // ---- exp2-folded softmax numerator
    float c0[4];
#pragma unroll
    for (int reg = 0; reg < 4; ++reg) c0[reg] = -mx[reg] * L2E64;
#pragma unroll
    for (int mt = 0; mt < 8; ++mt)
#pragma unroll
        for (int lt = 0; lt < 2; ++lt)
#pragma unroll
            for (int reg = 0; reg < 4; ++reg)
                acc[mt][lt][reg] = exp2f(fmaf(acc[mt][lt][reg], L2E64, c0[reg]));

    // ---- pm (row-marginal over l) + accumulate sum; write epA cols 0..31
    float sm[4] = {0.f, 0.f, 0.f, 0.f};
#pragma unroll
    for (int mt = 0; mt < 8; ++mt) {
        float tr[4];
#pragma unroll
        for (int reg = 0; reg < 4; ++reg) {
            float t = acc[mt][0][reg] + acc[mt][1][reg];
            t += __shfl_xor(t, 1, 64);
            t += __shfl_xor(t, 2, 64);
            t += __shfl_xor(t, 4, 64);
            t += __shfl_xor(t, 8, 64);
            tr[reg] = t;
            sm[reg] += t;
        }
        if ((lc >> 1) == mt) {
            float v0 = (lc & 1) ? tr[1] : tr[0];
            float v1 = (lc & 1) ? tr[3] : tr[2];
            epA[(wv * 4 + (lc & 1)) * PAD_K + mt * 4 + ko]     = f2bf(v0);
            epA[(wv * 4 + 2 + (lc & 1)) * PAD_K + mt * 4 + ko] = f2bf(v1);
        }
    }
    // complete sum over all m (ko groups)
#pragma unroll
    for (int reg = 0; reg < 4; ++reg) {
        sm[reg] += __shfl_xor(sm[reg], 16, 64);
        sm[reg] += __shfl_xor(sm[reg], 32, 64);
    }
    if (lane == 0) {
#pragma unroll
        for (int reg = 0; reg < 4; ++reg) sinv[wv * 4 + reg] = 1.0f / sm[reg];
    }

    // ---- pl (col-marginal over m); write epA cols 32..63
#pragma unroll
    for (int lt = 0; lt < 2; ++lt) {
        float pv[4];
#pragma unroll
        for (int reg = 0; reg < 4; ++reg) {
            float p = acc[0][lt][reg];
#pragma unroll
            for (int mt = 1; mt < 8; ++mt) p += acc[mt][lt][reg];
            p += __shfl_xor(p, 16, 64);
            p += __shfl_xor(p, 32, 64);
            pv[reg] = p;
        }
        float w  = (ko & 1) ? pv[1] : pv[0];
        float w2 = (ko & 1) ? pv[3] : pv[2];
        float ww = (ko & 2) ? w2 : w;
        epA[(wv * 4 + ko) * PAD_K + 32 + lt * 16 + lc] = f2bf(ww);
    }

    // ---- epilogue B-frags from sd/se (built pre-barrier; dd = wv*16+lc)
    const int dd = wv * 16 + lc;
    bf16x8 bd, be;
    {
        unsigned dv[8], ev[8];
#pragma unroll
        for (int j = 0; j < 8; ++j) {
            dv[j] = *reinterpret_cast<const unsigned short*>(&sd[(ko * 8 + j) * PAD_K + dd]);
            ev[j] = *reinterpret_cast<const unsigned short*>(&se[(ko * 8 + j) * PAD_K + dd]);
        }
        union { unsigned u[4]; bf16x8 v; } td, te;
#pragma unroll
        for (int j = 0; j < 4; ++j) {
            td.u[j] = __builtin_amdgcn_perm(dv[2 * j + 1], dv[2 * j], 0x05040100);
            te.u[j] = __builtin_amdgcn_perm(ev[2 * j + 1], ev[2 * j], 0x05040100);
        }
        bd = td.v; be = te.v;
    }
    __syncthreads();   // B2

    // ---- cooperative epilogue: z[0..15][dd] for this wave's dd slice
    bf16x8 apm = *reinterpret_cast<const bf16x8*>(&epA[lc * PAD_K + ko * 8]);
    bf16x8 apl = *reinterpret_cast<const bf16x8*>(&epA[lc * PAD_K + 32 + ko * 8]);
    f32x4 zacc = (f32x4){0.f, 0.f, 0.f, 0.f};
    zacc = __builtin_amdgcn_mfma_f32_16x16x32_bf16(apm, bd, zacc, 0, 0, 0);
    zacc = __builtin_amdgcn_mfma_f32_16x16x32_bf16(apl, be, zacc, 0, 0, 0);

#pragma unroll
    for (int reg = 0; reg < 4; ++reg) {
        int i = ko * 4 + reg;
        float invv = sinv[i];
        int t = nbase + i;
        z[((size_t)b * T_SEQ + t) * (NHEADS * DHEAD) + hd + dd] = f2bf(zacc[reg] * invv);
    }
}

// ---------------------------------------------------------------------------
extern "C" void kernel_launch(void* const* d_in, const int* in_sizes, int n_in,
                              void* d_out, int out_size, void* d_ws, size_t ws_size,
                              hipStream_t stream) {
    const float* x        = (const float*)d_in[0];
    const float* W_abcde  = (const float*)d_in[1];
    const float* b_abcde  = (const float*)d_in[2];
    const float* W_O      = (const float*)d_in[3];
    const float* b_O      = (const float*)d_in[4];
    float* out = (float*)d_out;

    char* ws = (char*)d_ws;
    short* abcde = (short*)ws;                                 // 4096x3840 bf16
    short* xb    = (short*)(ws + (size_t)31457280);            // 4096x768 bf16, reused as zb
    short* Wt    = (short*)(ws + (size_t)31457280 + 6291456);  // 3840x768 bf16, reused as WOt
    short* zb    = xb;
    short* WOt   = Wt;

    const int M = 2 * T_SEQ;  // 4096

    cast_bf16_kernel<<<dim3((M * DMODEL / 8 + 255) / 256), dim3(256), 0, stream>>>(
        x, xb, M * DMODEL);
    transpose_cast_kernel<<<dim3(NABCDE / 32, DMODEL / 32), dim3(256), 0, stream>>>(
        W_abcde, Wt, DMODEL, NABCDE);

    gemm_bf16_mfma<true><<<dim3(NABCDE / 128, M / 128), dim3(256), 0, stream>>>(
        xb, Wt, b_abcde, (void*)abcde, M, NABCDE, DMODEL);

    attn_kernel<<<dim3(2 * NHEADS * NWIN), dim3(256), 0, stream>>>(abcde, zb);

    transpose_cast_kernel<<<dim3(DMODEL / 32, DMODEL / 32), dim3(256), 0, stream>>>(
        W_O, WOt, DMODEL, DMODEL);

    gemm_bf16_mfma_n64<<<dim3(DMODEL / 64, M / 128), dim3(256), 0, stream>>>(
        zb, WOt, b_O, out, M, DMODEL, DMODEL);
}

// Round 6
// 188.213 us; speedup vs baseline: 1.2106x; 1.0461x over previous
//
#include <hip/hip_runtime.h>

#define T_SEQ   2048
#define NHEADS  12
#define DHEAD   64
#define WIN     16
#define WW      32
#define NWIN    128
#define DMODEL  768
#define NABCDE  3840
#define IGNORE_V (-1.0e6f)
#define PAD_K   72          // bf16 LDS row stride (144 B, 16B-aligned)
#define L2E64   0.022542110013890053f   // log2(e)/64

typedef float f32x4 __attribute__((ext_vector_type(4)));
typedef short bf16x8 __attribute__((ext_vector_type(8)));

__device__ __forceinline__ short f2bf(float f) {
    unsigned u = __float_as_uint(f);
    unsigned r = (u + 0x7FFF + ((u >> 16) & 1)) >> 16;   // RNE
    return (short)r;
}

__device__ __forceinline__ void gload_lds16(const short* g, short* l) {
    __builtin_amdgcn_global_load_lds(
        (const __attribute__((address_space(1))) void*)g,
        (__attribute__((address_space(3))) void*)l,
        16, 0, 0);
}

// ---------------------------------------------------------------------------
// merged prep: [0,1536) cast x -> xb; [1536,4416) transpose W_abcde -> Wt;
// [4416,4992) transpose W_O -> WOt.
// ---------------------------------------------------------------------------
__global__ __launch_bounds__(256) void prep_kernel(
    const float* __restrict__ x, const float* __restrict__ W_abcde,
    const float* __restrict__ W_O,
    short* __restrict__ xb, short* __restrict__ Wt, short* __restrict__ WOt)
{
    __shared__ float tile[32][33];
    const int blk = blockIdx.x;
    const int tid = threadIdx.x;

    if (blk < 1536) {                       // cast x (4096x768 = 3145728 elems)
        int i = (blk * 256 + tid) * 8;
        float4 a = *reinterpret_cast<const float4*>(&x[i]);
        float4 b = *reinterpret_cast<const float4*>(&x[i + 4]);
        union { short s[8]; uint4 u; } r;
        r.s[0] = f2bf(a.x); r.s[1] = f2bf(a.y); r.s[2] = f2bf(a.z); r.s[3] = f2bf(a.w);
        r.s[4] = f2bf(b.x); r.s[5] = f2bf(b.y); r.s[6] = f2bf(b.z); r.s[7] = f2bf(b.w);
        *reinterpret_cast<uint4*>(&xb[i]) = r.u;
        return;
    }
    const float* W; short* Wo; int N, bx, by;
    if (blk < 4416) {                       // W_abcde: 120x24 tiles
        int t = blk - 1536;
        W = W_abcde; Wo = Wt; N = NABCDE;
        bx = (t % 120) * 32; by = (t / 120) * 32;
    } else {                                // W_O: 24x24 tiles
        int t = blk - 4416;
        W = W_O; Wo = WOt; N = DMODEL;
        bx = (t % 24) * 32; by = (t / 24) * 32;
    }
    const int tx = tid & 31, ty = tid >> 5;
#pragma unroll
    for (int r = 0; r < 32; r += 8)
        tile[ty + r][tx] = W[(size_t)(by + ty + r) * N + bx + tx];
    __syncthreads();
#pragma unroll
    for (int r = 0; r < 32; r += 8)
        Wo[(size_t)(bx + ty + r) * DMODEL + by + tx] = f2bf(tile[tx][ty + r]);
}

// ---------------------------------------------------------------------------
// bf16 MFMA GEMM 128x128, BK=64 via dual 32-wide LDS buffers:
// 8 glds + 32 MFMAs between barrier pairs. BF16OUT selects output type.
// ---------------------------------------------------------------------------
template <bool BF16OUT>
__global__ __launch_bounds__(256) void gemm_bf16_mfma(
    const short* __restrict__ A, const short* __restrict__ Bt,
    const float* __restrict__ bias, void* __restrict__ Cv,
    int M, int N, int K)
{
    __shared__ short As[2][128 * 32];
    __shared__ short Bs[2][128 * 32];

    const int tid  = threadIdx.x;
    const int wave = tid >> 6;
    const int lane = tid & 63;
    const int bm = blockIdx.y * 128;
    const int bn = blockIdx.x * 128;

    const int st_row = lane >> 2;
    const int st_col = (lane & 3) * 8;
    const int fr_m = lane & 15;
    const int fr_k = (lane >> 4) * 8;
    const int wm = (wave >> 1) * 64;
    const int wn = (wave & 1) * 64;

    f32x4 acc[4][4];
#pragma unroll
    for (int mi = 0; mi < 4; ++mi)
#pragma unroll
        for (int ni = 0; ni < 4; ++ni) acc[mi][ni] = (f32x4){0.f, 0.f, 0.f, 0.f};

    const short* Ab0 = A  + (size_t)(bm + wave * 32 + st_row)      * K + st_col;
    const short* Ab1 = A  + (size_t)(bm + wave * 32 + 16 + st_row) * K + st_col;
    const short* Bb0 = Bt + (size_t)(bn + wave * 32 + st_row)      * K + st_col;
    const short* Bb1 = Bt + (size_t)(bn + wave * 32 + 16 + st_row) * K + st_col;

    for (int k0 = 0; k0 < K; k0 += 64) {
#pragma unroll
        for (int kt = 0; kt < 2; ++kt) {
            int kk = k0 + kt * 32;
            gload_lds16(Ab0 + kk, &As[kt][(wave * 32)      * 32]);
            gload_lds16(Ab1 + kk, &As[kt][(wave * 32 + 16) * 32]);
            gload_lds16(Bb0 + kk, &Bs[kt][(wave * 32)      * 32]);
            gload_lds16(Bb1 + kk, &Bs[kt][(wave * 32 + 16) * 32]);
        }
        __syncthreads();

#pragma unroll
        for (int kt = 0; kt < 2; ++kt) {
            bf16x8 af[4], bf[4];
#pragma unroll
            for (int mi = 0; mi < 4; ++mi)
                af[mi] = *reinterpret_cast<const bf16x8*>(
                    &As[kt][(wm + mi * 16 + fr_m) * 32 + fr_k]);
#pragma unroll
            for (int ni = 0; ni < 4; ++ni)
                bf[ni] = *reinterpret_cast<const bf16x8*>(
                    &Bs[kt][(wn + ni * 16 + fr_m) * 32 + fr_k]);
#pragma unroll
            for (int mi = 0; mi < 4; ++mi)
#pragma unroll
                for (int ni = 0; ni < 4; ++ni)
                    acc[mi][ni] = __builtin_amdgcn_mfma_f32_16x16x32_bf16(
                        af[mi], bf[ni], acc[mi][ni], 0, 0, 0);
        }
        __syncthreads();
    }

    float bv[4];
#pragma unroll
    for (int ni = 0; ni < 4; ++ni)
        bv[ni] = bias[bn + wn + ni * 16 + (lane & 15)];
#pragma unroll
    for (int mi = 0; mi < 4; ++mi) {
        int rbase = bm + wm + mi * 16 + (lane >> 4) * 4;
#pragma unroll
        for (int r = 0; r < 4; ++r) {
            size_t off = (size_t)(rbase + r) * N + bn + wn + (lane & 15);
#pragma unroll
            for (int ni = 0; ni < 4; ++ni) {
                float val = acc[mi][ni][r] + bv[ni];
                if (BF16OUT) ((short*)Cv)[off + ni * 16] = f2bf(val);
                else         ((float*)Cv)[off + ni * 16] = val;
            }
        }
    }
}

// ---------------------------------------------------------------------------
// bf16 MFMA GEMM 128x64 tile, BK=64 dual-buffer (N=768 -> 384 blocks), fp32.
// ---------------------------------------------------------------------------
__global__ __launch_bounds__(256) void gemm_bf16_mfma_n64(
    const short* __restrict__ A, const short* __restrict__ Bt,
    const float* __restrict__ bias, float* __restrict__ C,
    int M, int N, int K)
{
    __shared__ short As[2][128 * 32];
    __shared__ short Bs[2][64 * 32];

    const int tid  = threadIdx.x;
    const int wave = tid >> 6;
    const int lane = tid & 63;
    const int bm = blockIdx.y * 128;
    const int bn = blockIdx.x * 64;

    const int st_row = lane >> 2;
    const int st_col = (lane & 3) * 8;
    const int fr_m = lane & 15;
    const int fr_k = (lane >> 4) * 8;
    const int wm = wave * 32;
    const bool doB = (wave < 2);

    f32x4 acc[2][4];
#pragma unroll
    for (int mi = 0; mi < 2; ++mi)
#pragma unroll
        for (int ni = 0; ni < 4; ++ni) acc[mi][ni] = (f32x4){0.f, 0.f, 0.f, 0.f};

    const short* Ab0 = A  + (size_t)(bm + wm + st_row)      * K + st_col;
    const short* Ab1 = A  + (size_t)(bm + wm + 16 + st_row) * K + st_col;
    const short* Bb0 = Bt + (size_t)(bn + (wave & 1) * 32 + st_row)      * K + st_col;
    const short* Bb1 = Bt + (size_t)(bn + (wave & 1) * 32 + 16 + st_row) * K + st_col;

    for (int k0 = 0; k0 < K; k0 += 64) {
#pragma unroll
        for (int kt = 0; kt < 2; ++kt) {
            int kk = k0 + kt * 32;
            gload_lds16(Ab0 + kk, &As[kt][(wm)      * 32]);
            gload_lds16(Ab1 + kk, &As[kt][(wm + 16) * 32]);
            if (doB) {
                gload_lds16(Bb0 + kk, &Bs[kt][((wave & 1) * 32)      * 32]);
                gload_lds16(Bb1 + kk, &Bs[kt][((wave & 1) * 32 + 16) * 32]);
            }
        }
        __syncthreads();

#pragma unroll
        for (int kt = 0; kt < 2; ++kt) {
            bf16x8 af[2], bf[4];
#pragma unroll
            for (int mi = 0; mi < 2; ++mi)
                af[mi] = *reinterpret_cast<const bf16x8*>(
                    &As[kt][(wm + mi * 16 + fr_m) * 32 + fr_k]);
#pragma unroll
            for (int ni = 0; ni < 4; ++ni)
                bf[ni] = *reinterpret_cast<const bf16x8*>(
                    &Bs[kt][(ni * 16 + fr_m) * 32 + fr_k]);
#pragma unroll
            for (int mi = 0; mi < 2; ++mi)
#pragma unroll
                for (int ni = 0; ni < 4; ++ni)
                    acc[mi][ni] = __builtin_amdgcn_mfma_f32_16x16x32_bf16(
                        af[mi], bf[ni], acc[mi][ni], 0, 0, 0);
        }
        __syncthreads();
    }

    float bv[4];
#pragma unroll
    for (int ni = 0; ni < 4; ++ni)
        bv[ni] = bias[bn + ni * 16 + (lane & 15)];
#pragma unroll
    for (int mi = 0; mi < 2; ++mi) {
        int rbase = bm + wm + mi * 16 + (lane >> 4) * 4;
#pragma unroll
        for (int r = 0; r < 4; ++r) {
            size_t off = (size_t)(rbase + r) * N + bn + (lane & 15);
#pragma unroll
            for (int ni = 0; ni < 4; ++ni)
                C[off + ni * 16] = acc[mi][ni][r] + bv[ni];
        }
    }
}

// ---------------------------------------------------------------------------
// Windowed trittention, wave-private softmax (round-5 structure).
// Wave wv owns queries wv*4..wv*4+3; MFMA rows = m_local*4 + i_local.
// cfrag pre-split into float pairs to cheapen the bmul repack.
// ---------------------------------------------------------------------------
__global__ __launch_bounds__(256) void attn_kernel(
    const short* __restrict__ abcde, short* __restrict__ z)
{
    const int blk = blockIdx.x;
    const int n  = blk & (NWIN - 1);
    const int bh = blk >> 7;
    const int b  = bh / NHEADS;
    const int h  = bh % NHEADS;

    __shared__ short sc[WIN * PAD_K];
    __shared__ short sa[WW * PAD_K];
    __shared__ short sb[WW * PAD_K];
    __shared__ short sd[WW * PAD_K];
    __shared__ short se[WW * PAD_K];
    __shared__ short epA[WIN * PAD_K];     // [i][0..31]=pm, [32..63]=pl (bf16, unnorm)
    __shared__ float sinv[WIN];

    const int tid = threadIdx.x;
    const size_t rowbase = ((size_t)b * T_SEQ) * NABCDE;
    const int hd = h * DHEAD;

    // ---- staging
    if (tid < 128) {
        int row = tid >> 3, ch = (tid & 7) * 8;
        *reinterpret_cast<uint4*>(&sc[row * PAD_K + ch]) =
            *reinterpret_cast<const uint4*>(
                &abcde[rowbase + (size_t)(n * WIN + row) * NABCDE + 2 * DMODEL + hd + ch]);
    }
    {
        int row = tid >> 3, ch = (tid & 7) * 8;
        int t = n * WIN - WIN + row;
        uint4 va = {0u, 0u, 0u, 0u}, vb = va, vd = va, ve = va;
        if (t >= 0) {
            size_t base = rowbase + (size_t)t * NABCDE + hd + ch;
            va = *reinterpret_cast<const uint4*>(&abcde[base + 0 * DMODEL]);
            vb = *reinterpret_cast<const uint4*>(&abcde[base + 1 * DMODEL]);
            vd = *reinterpret_cast<const uint4*>(&abcde[base + 3 * DMODEL]);
            ve = *reinterpret_cast<const uint4*>(&abcde[base + 4 * DMODEL]);
        }
        *reinterpret_cast<uint4*>(&sa[row * PAD_K + ch]) = va;
        *reinterpret_cast<uint4*>(&sb[row * PAD_K + ch]) = vb;
        *reinterpret_cast<uint4*>(&sd[row * PAD_K + ch]) = vd;
        *reinterpret_cast<uint4*>(&se[row * PAD_K + ch]) = ve;
    }
    __syncthreads();   // B1

    const int wv = tid >> 6;
    const int lane = tid & 63;
    const int lc = lane & 15;
    const int ko = lane >> 4;

    // ---- c fragment pre-split into float pairs; b fragments raw
    float cxl[2][4], cxh[2][4];
    bf16x8 bfrag[2][2];
#pragma unroll
    for (int kt = 0; kt < 2; ++kt) {
        union { bf16x8 v; unsigned u[4]; } Cf;
        Cf.v = *reinterpret_cast<const bf16x8*>(
            &sc[(wv * 4 + (lc & 3)) * PAD_K + kt * 32 + ko * 8]);
#pragma unroll
        for (int j = 0; j < 4; ++j) {
            cxl[kt][j] = __uint_as_float(Cf.u[j] << 16);
            cxh[kt][j] = __uint_as_float(Cf.u[j] & 0xffff0000u);
        }
        bfrag[0][kt] = *reinterpret_cast<const bf16x8*>(&sb[lc * PAD_K + kt * 32 + ko * 8]);
        bfrag[1][kt] = *reinterpret_cast<const bf16x8*>(&sb[(16 + lc) * PAD_K + kt * 32 + ko * 8]);
    }

    f32x4 acc[8][2];
#pragma unroll
    for (int mt = 0; mt < 8; ++mt) {
        acc[mt][0] = (f32x4){0.f, 0.f, 0.f, 0.f};
        acc[mt][1] = (f32x4){0.f, 0.f, 0.f, 0.f};
    }
#pragma unroll
    for (int mt = 0; mt < 8; ++mt) {
#pragma unroll
        for (int kt = 0; kt < 2; ++kt) {
            union { bf16x8 v; unsigned u[4]; } Ar, Rf;
            Ar.v = *reinterpret_cast<const bf16x8*>(
                &sa[(mt * 4 + (lc >> 2)) * PAD_K + kt * 32 + ko * 8]);
#pragma unroll
            for (int j = 0; j < 4; ++j) {
                float yl = __uint_as_float(Ar.u[j] << 16);
                float yh = __uint_as_float(Ar.u[j] & 0xffff0000u);
                unsigned pl = __float_as_uint(cxl[kt][j] * yl);
                unsigned ph = __float_as_uint(cxh[kt][j] * yh);
                Rf.u[j] = __builtin_amdgcn_perm(ph, pl, 0x07060302);
            }
            acc[mt][0] = __builtin_amdgcn_mfma_f32_16x16x32_bf16(Rf.v, bfrag[0][kt], acc[mt][0], 0, 0, 0);
            acc[mt][1] = __builtin_amdgcn_mfma_f32_16x16x32_bf16(Rf.v, bfrag[1][kt], acc[mt][1], 0, 0, 0);
        }
    }

    // ---- mask + per-query max (i = wv*4+reg, m = mt*4+ko, l = lt*16+lc)
    const int nbase = n * WIN;
    int bbl_h[2];
#pragma unroll
    for (int lt = 0; lt < 2; ++lt) {
        int l = lt * 16 + lc;
        bbl_h[lt] = (n == 0 && l < WIN) ? 0 : (nbase - WIN + l);
    }
    float mx[4] = {-3.4e38f, -3.4e38f, -3.4e38f, -3.4e38f};
#pragma unroll
    for (int mt = 0; mt < 8; ++mt) {
        int m = mt * 4 + ko;
        int bbm = (n == 0 && m < WIN) ? 0 : (nbase - WIN + m);
#pragma unroll
        for (int lt = 0; lt < 2; ++lt) {
            bool mgt = bbl_h[lt] > bbm;
#pragma unroll
            for (int reg = 0; reg < 4; ++reg) {
                int tq = nbase + wv * 4 + reg;
                float v = acc[mt][lt][reg];
                bool keep = (tq >= bbl_h[lt]) && mgt;
                if (!keep || v == 0.0f) v = IGNORE_V;
                acc[mt][lt][reg] = v;
                mx[reg] = fmaxf(mx[reg], v);
            }
        }
    }
#pragma unroll
    for (int reg = 0; reg < 4; ++reg) {
#pragma unroll
        for (int off = 1; off < 64; off <<= 1)
            mx[reg] = fmaxf(mx[reg], __shfl_xor(mx[reg], off, 64));
    }

    // ---- exp2-folded softmax numerator
    float c0[4];
#pragma unroll
    for (int reg = 0; reg < 4; ++reg) c0[reg] = -mx[reg] * L2E64;
#pragma unroll
    for (int mt = 0; mt < 8; ++mt)
#pragma unroll
        for (int lt = 0; lt < 2; ++lt)
#pragma unroll
            for (int reg = 0; reg < 4; ++reg)
                acc[mt][lt][reg] = exp2f(fmaf(acc[mt][lt][reg], L2E64, c0[reg]));

    // ---- pm (row-marginal over l) + sum; write epA cols 0..31
    float sm[4] = {0.f, 0.f, 0.f, 0.f};
#pragma unroll
    for (int mt = 0; mt < 8; ++mt) {
        float tr[4];
#pragma unroll
        for (int reg = 0; reg < 4; ++reg) {
            float t = acc[mt][0][reg] + acc[mt][1][reg];
            t += __shfl_xor(t, 1, 64);
            t += __shfl_xor(t, 2, 64);
            t += __shfl_xor(t, 4, 64);
            t += __shfl_xor(t, 8, 64);
            tr[reg] = t;
            sm[reg] += t;
        }
        if ((lc >> 1) == mt) {
            float v0 = (lc & 1) ? tr[1] : tr[0];
            float v1 = (lc & 1) ? tr[3] : tr[2];
            epA[(wv * 4 + (lc & 1)) * PAD_K + mt * 4 + ko]     = f2bf(v0);
            epA[(wv * 4 + 2 + (lc & 1)) * PAD_K + mt * 4 + ko] = f2bf(v1);
        }
    }
#pragma unroll
    for (int reg = 0; reg < 4; ++reg) {
        sm[reg] += __shfl_xor(sm[reg], 16, 64);
        sm[reg] += __shfl_xor(sm[reg], 32, 64);
    }
    if (lane == 0) {
#pragma unroll
        for (int reg = 0; reg < 4; ++reg) sinv[wv * 4 + reg] = 1.0f / sm[reg];
    }

    // ---- pl (col-marginal over m); write epA cols 32..63
#pragma unroll
    for (int lt = 0; lt < 2; ++lt) {
        float pv[4];
#pragma unroll
        for (int reg = 0; reg < 4; ++reg) {
            float p = acc[0][lt][reg];
#pragma unroll
            for (int mt = 1; mt < 8; ++mt) p += acc[mt][lt][reg];
            p += __shfl_xor(p, 16, 64);
            p += __shfl_xor(p, 32, 64);
            pv[reg] = p;
        }
        float w  = (ko & 1) ? pv[1] : pv[0];
        float w2 = (ko & 1) ? pv[3] : pv[2];
        float ww = (ko & 2) ? w2 : w;
        epA[(wv * 4 + ko) * PAD_K + 32 + lt * 16 + lc] = f2bf(ww);
    }

    // ---- epilogue B-frags from sd/se (pre-barrier; dd = wv*16+lc)
    const int dd = wv * 16 + lc;
    bf16x8 bd, be;
    {
        unsigned dv[8], ev[8];
#pragma unroll
        for (int j = 0; j < 8; ++j) {
            dv[j] = *reinterpret_cast<const unsigned short*>(&sd[(ko * 8 + j) * PAD_K + dd]);
            ev[j] = *reinterpret_cast<const unsigned short*>(&se[(ko * 8 + j) * PAD_K + dd]);
        }
        union { unsigned u[4]; bf16x8 v; } td, te;
#pragma unroll
        for (int j = 0; j < 4; ++j) {
            td.u[j] = __builtin_amdgcn_perm(dv[2 * j + 1], dv[2 * j], 0x05040100);
            te.u[j] = __builtin_amdgcn_perm(ev[2 * j + 1], ev[2 * j], 0x05040100);
        }
        bd = td.v; be = te.v;
    }
    __syncthreads();   // B2

    // ---- cooperative epilogue MFMA
    bf16x8 apm = *reinterpret_cast<const bf16x8*>(&epA[lc * PAD_K + ko * 8]);
    bf16x8 apl = *reinterpret_cast<const bf16x8*>(&epA[lc * PAD_K + 32 + ko * 8]);
    f32x4 zacc = (f32x4){0.f, 0.f, 0.f, 0.f};
    zacc = __builtin_amdgcn_mfma_f32_16x16x32_bf16(apm, bd, zacc, 0, 0, 0);
    zacc = __builtin_amdgcn_mfma_f32_16x16x32_bf16(apl, be, zacc, 0, 0, 0);

#pragma unroll
    for (int reg = 0; reg < 4; ++reg) {
        int i = ko * 4 + reg;
        z[((size_t)b * T_SEQ + nbase + i) * (NHEADS * DHEAD) + hd + dd] =
            f2bf(zacc[reg] * sinv[i]);
    }
}

// ---------------------------------------------------------------------------
extern "C" void kernel_launch(void* const* d_in, const int* in_sizes, int n_in,
                              void* d_out, int out_size, void* d_ws, size_t ws_size,
                              hipStream_t stream) {
    const float* x        = (const float*)d_in[0];
    const float* W_abcde  = (const float*)d_in[1];
    const float* b_abcde  = (const float*)d_in[2];
    const float* W_O      = (const float*)d_in[3];
    const float* b_O      = (const float*)d_in[4];
    float* out = (float*)d_out;

    char* ws = (char*)d_ws;
    short* abcde = (short*)ws;                                  // 4096x3840 bf16 (31.5 MB)
    short* xb    = (short*)(ws + (size_t)31457280);             // 4096x768 bf16, reused as zb
    short* Wt    = (short*)(ws + (size_t)31457280 + 6291456);   // 3840x768 bf16
    short* WOt   = (short*)(ws + (size_t)31457280 + 6291456 + 5898240); // 768x768 bf16
    short* zb    = xb;

    const int M = 2 * T_SEQ;  // 4096

    // prep: cast x + transpose both weights (one kernel, 4992 blocks)
    prep_kernel<<<dim3(4992), dim3(256), 0, stream>>>(
        x, W_abcde, W_O, xb, Wt, WOt);

    gemm_bf16_mfma<true><<<dim3(NABCDE / 128, M / 128), dim3(256), 0, stream>>>(
        xb, Wt, b_abcde, (void*)abcde, M, NABCDE, DMODEL);

    attn_kernel<<<dim3(2 * NHEADS * NWIN), dim3(256), 0, stream>>>(abcde, zb);

    gemm_bf16_mfma_n64<<<dim3(DMODEL / 64, M / 128), dim3(256), 0, stream>>>(
        zb, WOt, b_O, out, M, DMODEL, DMODEL);
}

// Round 7
// 180.811 us; speedup vs baseline: 1.2602x; 1.0409x over previous
//
#include <hip/hip_runtime.h>

#define T_SEQ   2048
#define NHEADS  12
#define DHEAD   64
#define WIN     16
#define WW      32
#define NWIN    128
#define DMODEL  768
#define NABCDE  3840
#define IGNORE_V (-1.0e6f)
#define PAD_K   72          // bf16 LDS row stride (144 B, 16B-aligned)
#define L2E64   0.022542110013890053f   // log2(e)/64

typedef float f32x4 __attribute__((ext_vector_type(4)));
typedef short bf16x8 __attribute__((ext_vector_type(8)));

__device__ __forceinline__ short f2bf(float f) {
    unsigned u = __float_as_uint(f);
    unsigned r = (u + 0x7FFF + ((u >> 16) & 1)) >> 16;   // RNE
    return (short)r;
}

__device__ __forceinline__ void gload_lds16(const short* g, short* l) {
    __builtin_amdgcn_global_load_lds(
        (const __attribute__((address_space(1))) void*)g,
        (__attribute__((address_space(3))) void*)l,
        16, 0, 0);
}

// ---------------------------------------------------------------------------
// merged prep: [0,1536) cast x -> xb; [1536,4416) transpose W_abcde -> Wt;
// [4416,4992) transpose W_O -> WOt.
// ---------------------------------------------------------------------------
__global__ __launch_bounds__(256) void prep_kernel(
    const float* __restrict__ x, const float* __restrict__ W_abcde,
    const float* __restrict__ W_O,
    short* __restrict__ xb, short* __restrict__ Wt, short* __restrict__ WOt)
{
    __shared__ float tile[32][33];
    const int blk = blockIdx.x;
    const int tid = threadIdx.x;

    if (blk < 1536) {
        int i = (blk * 256 + tid) * 8;
        float4 a = *reinterpret_cast<const float4*>(&x[i]);
        float4 b = *reinterpret_cast<const float4*>(&x[i + 4]);
        union { short s[8]; uint4 u; } r;
        r.s[0] = f2bf(a.x); r.s[1] = f2bf(a.y); r.s[2] = f2bf(a.z); r.s[3] = f2bf(a.w);
        r.s[4] = f2bf(b.x); r.s[5] = f2bf(b.y); r.s[6] = f2bf(b.z); r.s[7] = f2bf(b.w);
        *reinterpret_cast<uint4*>(&xb[i]) = r.u;
        return;
    }
    const float* W; short* Wo; int N, bx, by;
    if (blk < 4416) {
        int t = blk - 1536;
        W = W_abcde; Wo = Wt; N = NABCDE;
        bx = (t % 120) * 32; by = (t / 120) * 32;
    } else {
        int t = blk - 4416;
        W = W_O; Wo = WOt; N = DMODEL;
        bx = (t % 24) * 32; by = (t / 24) * 32;
    }
    const int tx = tid & 31, ty = tid >> 5;
#pragma unroll
    for (int r = 0; r < 32; r += 8)
        tile[ty + r][tx] = W[(size_t)(by + ty + r) * N + bx + tx];
    __syncthreads();
#pragma unroll
    for (int r = 0; r < 32; r += 8)
        Wo[(size_t)(bx + ty + r) * DMODEL + by + tx] = f2bf(tile[tx][ty + r]);
}

// ---------------------------------------------------------------------------
// bf16 MFMA GEMM, 128x64 tile, BK=64 dual 32-wide LDS buffers, balanced
// staging (24 glds chunks, 6 per wave). Waves 4x1 over M (32 rows each,
// full 64-wide N). BF16OUT selects output type.
// ---------------------------------------------------------------------------
template <bool BF16OUT>
__global__ __launch_bounds__(256) void gemm_bf16_n64(
    const short* __restrict__ A, const short* __restrict__ Bt,
    const float* __restrict__ bias, void* __restrict__ Cv,
    int M, int N, int K)
{
    __shared__ short As[2][128 * 32];
    __shared__ short Bs[2][64 * 32];

    const int tid  = threadIdx.x;
    const int wave = tid >> 6;
    const int lane = tid & 63;
    const int bm = blockIdx.y * 128;
    const int bn = blockIdx.x * 64;

    const int st_row = lane >> 2;          // 0..15
    const int st_col = (lane & 3) * 8;     // 0,8,16,24
    const int fr_m = lane & 15;
    const int fr_k = (lane >> 4) * 8;
    const int wm = wave * 32;

    // balanced staging assignment: chunk c = wave*6 + j
    const short* gsrc[6];
    short* ldst[6];
#pragma unroll
    for (int j = 0; j < 6; ++j) {
        int c = wave * 6 + j;
        if (c < 16) {                      // A: kt = c>>3, rowgroup = c&7
            int kt = c >> 3, rg = c & 7;
            gsrc[j] = A + (size_t)(bm + rg * 16 + st_row) * K + kt * 32 + st_col;
            ldst[j] = &As[kt][(rg * 16) * 32];
        } else {                           // B: kt = (c-16)>>2, rowgroup = (c-16)&3
            int cb = c - 16;
            int kt = cb >> 2, rg = cb & 3;
            gsrc[j] = Bt + (size_t)(bn + rg * 16 + st_row) * K + kt * 32 + st_col;
            ldst[j] = &Bs[kt][(rg * 16) * 32];
        }
    }

    f32x4 acc[2][4];
#pragma unroll
    for (int mi = 0; mi < 2; ++mi)
#pragma unroll
        for (int ni = 0; ni < 4; ++ni) acc[mi][ni] = (f32x4){0.f, 0.f, 0.f, 0.f};

    for (int k0 = 0; k0 < K; k0 += 64) {
#pragma unroll
        for (int j = 0; j < 6; ++j) gload_lds16(gsrc[j] + k0, ldst[j]);
        __syncthreads();

#pragma unroll
        for (int kt = 0; kt < 2; ++kt) {
            bf16x8 af[2], bf[4];
#pragma unroll
            for (int mi = 0; mi < 2; ++mi)
                af[mi] = *reinterpret_cast<const bf16x8*>(
                    &As[kt][(wm + mi * 16 + fr_m) * 32 + fr_k]);
#pragma unroll
            for (int ni = 0; ni < 4; ++ni)
                bf[ni] = *reinterpret_cast<const bf16x8*>(
                    &Bs[kt][(ni * 16 + fr_m) * 32 + fr_k]);
#pragma unroll
            for (int mi = 0; mi < 2; ++mi)
#pragma unroll
                for (int ni = 0; ni < 4; ++ni)
                    acc[mi][ni] = __builtin_amdgcn_mfma_f32_16x16x32_bf16(
                        af[mi], bf[ni], acc[mi][ni], 0, 0, 0);
        }
        __syncthreads();
    }

    float bv[4];
#pragma unroll
    for (int ni = 0; ni < 4; ++ni)
        bv[ni] = bias[bn + ni * 16 + (lane & 15)];
#pragma unroll
    for (int mi = 0; mi < 2; ++mi) {
        int rbase = bm + wm + mi * 16 + (lane >> 4) * 4;
#pragma unroll
        for (int r = 0; r < 4; ++r) {
            size_t off = (size_t)(rbase + r) * N + bn + (lane & 15);
#pragma unroll
            for (int ni = 0; ni < 4; ++ni) {
                float val = acc[mi][ni][r] + bv[ni];
                if (BF16OUT) ((short*)Cv)[off + ni * 16] = f2bf(val);
                else         ((float*)Cv)[off + ni * 16] = val;
            }
        }
    }
}

// ---------------------------------------------------------------------------
// Windowed trittention, wave-private softmax + pair-tree pm reduction.
// Wave wv owns queries wv*4..wv*4+3; score MFMA rows = m_local*4 + i_local.
// C-layout: i_local = reg, m_local = ko, l = lt*16+lc.
// ---------------------------------------------------------------------------
__global__ __launch_bounds__(256) void attn_kernel(
    const short* __restrict__ abcde, short* __restrict__ z)
{
    const int blk = blockIdx.x;
    const int n  = blk & (NWIN - 1);
    const int bh = blk >> 7;
    const int b  = bh / NHEADS;
    const int h  = bh % NHEADS;

    __shared__ short sc[WIN * PAD_K];
    __shared__ short sa[WW * PAD_K];
    __shared__ short sb[WW * PAD_K];
    __shared__ short sd[WW * PAD_K];
    __shared__ short se[WW * PAD_K];
    __shared__ short epA[WIN * PAD_K];     // [i][0..31]=pm, [32..63]=pl (bf16, unnorm)
    __shared__ float sinv[WIN];

    const int tid = threadIdx.x;
    const size_t rowbase = ((size_t)b * T_SEQ) * NABCDE;
    const int hd = h * DHEAD;

    // ---- staging
    if (tid < 128) {
        int row = tid >> 3, ch = (tid & 7) * 8;
        *reinterpret_cast<uint4*>(&sc[row * PAD_K + ch]) =
            *reinterpret_cast<const uint4*>(
                &abcde[rowbase + (size_t)(n * WIN + row) * NABCDE + 2 * DMODEL + hd + ch]);
    }
    {
        int row = tid >> 3, ch = (tid & 7) * 8;
        int t = n * WIN - WIN + row;
        uint4 va = {0u, 0u, 0u, 0u}, vb = va, vd = va, ve = va;
        if (t >= 0) {
            size_t base = rowbase + (size_t)t * NABCDE + hd + ch;
            va = *reinterpret_cast<const uint4*>(&abcde[base + 0 * DMODEL]);
            vb = *reinterpret_cast<const uint4*>(&abcde[base + 1 * DMODEL]);
            vd = *reinterpret_cast<const uint4*>(&abcde[base + 3 * DMODEL]);
            ve = *reinterpret_cast<const uint4*>(&abcde[base + 4 * DMODEL]);
        }
        *reinterpret_cast<uint4*>(&sa[row * PAD_K + ch]) = va;
        *reinterpret_cast<uint4*>(&sb[row * PAD_K + ch]) = vb;
        *reinterpret_cast<uint4*>(&sd[row * PAD_K + ch]) = vd;
        *reinterpret_cast<uint4*>(&se[row * PAD_K + ch]) = ve;
    }
    __syncthreads();   // B1

    const int wv = tid >> 6;
    const int lane = tid & 63;
    const int lc = lane & 15;
    const int ko = lane >> 4;

    // ---- c fragment pre-split into float pairs; b fragments raw
    float cxl[2][4], cxh[2][4];
    bf16x8 bfrag[2][2];
#pragma unroll
    for (int kt = 0; kt < 2; ++kt) {
        union { bf16x8 v; unsigned u[4]; } Cf;
        Cf.v = *reinterpret_cast<const bf16x8*>(
            &sc[(wv * 4 + (lc & 3)) * PAD_K + kt * 32 + ko * 8]);
#pragma unroll
        for (int j = 0; j < 4; ++j) {
            cxl[kt][j] = __uint_as_float(Cf.u[j] << 16);
            cxh[kt][j] = __uint_as_float(Cf.u[j] & 0xffff0000u);
        }
        bfrag[0][kt] = *reinterpret_cast<const bf16x8*>(&sb[lc * PAD_K + kt * 32 + ko * 8]);
        bfrag[1][kt] = *reinterpret_cast<const bf16x8*>(&sb[(16 + lc) * PAD_K + kt * 32 + ko * 8]);
    }

    f32x4 acc[8][2];
#pragma unroll
    for (int mt = 0; mt < 8; ++mt) {
        acc[mt][0] = (f32x4){0.f, 0.f, 0.f, 0.f};
        acc[mt][1] = (f32x4){0.f, 0.f, 0.f, 0.f};
    }
#pragma unroll
    for (int mt = 0; mt < 8; ++mt) {
#pragma unroll
        for (int kt = 0; kt < 2; ++kt) {
            union { bf16x8 v; unsigned u[4]; } Ar, Rf;
            Ar.v = *reinterpret_cast<const bf16x8*>(
                &sa[(mt * 4 + (lc >> 2)) * PAD_K + kt * 32 + ko * 8]);
#pragma unroll
            for (int j = 0; j < 4; ++j) {
                float yl = __uint_as_float(Ar.u[j] << 16);
                float yh = __uint_as_float(Ar.u[j] & 0xffff0000u);
                unsigned pl = __float_as_uint(cxl[kt][j] * yl);
                unsigned ph = __float_as_uint(cxh[kt][j] * yh);
                Rf.u[j] = __builtin_amdgcn_perm(ph, pl, 0x07060302);
            }
            acc[mt][0] = __builtin_amdgcn_mfma_f32_16x16x32_bf16(Rf.v, bfrag[0][kt], acc[mt][0], 0, 0, 0);
            acc[mt][1] = __builtin_amdgcn_mfma_f32_16x16x32_bf16(Rf.v, bfrag[1][kt], acc[mt][1], 0, 0, 0);
        }
    }

    // ---- mask + per-query max
    const int nbase = n * WIN;
    int bbl_h[2];
#pragma unroll
    for (int lt = 0; lt < 2; ++lt) {
        int l = lt * 16 + lc;
        bbl_h[lt] = (n == 0 && l < WIN) ? 0 : (nbase - WIN + l);
    }
    float mx[4] = {-3.4e38f, -3.4e38f, -3.4e38f, -3.4e38f};
#pragma unroll
    for (int mt = 0; mt < 8; ++mt) {
        int m = mt * 4 + ko;
        int bbm = (n == 0 && m < WIN) ? 0 : (nbase - WIN + m);
#pragma unroll
        for (int lt = 0; lt < 2; ++lt) {
            bool mgt = bbl_h[lt] > bbm;
#pragma unroll
            for (int reg = 0; reg < 4; ++reg) {
                int tq = nbase + wv * 4 + reg;
                float v = acc[mt][lt][reg];
                bool keep = (tq >= bbl_h[lt]) && mgt;
                if (!keep || v == 0.0f) v = IGNORE_V;
                acc[mt][lt][reg] = v;
                mx[reg] = fmaxf(mx[reg], v);
            }
        }
    }
#pragma unroll
    for (int reg = 0; reg < 4; ++reg) {
#pragma unroll
        for (int off = 1; off < 64; off <<= 1)
            mx[reg] = fmaxf(mx[reg], __shfl_xor(mx[reg], off, 64));
    }

    // ---- exp2-folded softmax numerator
    float c0[4];
#pragma unroll
    for (int reg = 0; reg < 4; ++reg) c0[reg] = -mx[reg] * L2E64;
#pragma unroll
    for (int mt = 0; mt < 8; ++mt)
#pragma unroll
        for (int lt = 0; lt < 2; ++lt)
#pragma unroll
            for (int reg = 0; reg < 4; ++reg)
                acc[mt][lt][reg] = exp2f(fmaf(acc[mt][lt][reg], L2E64, c0[reg]));

    // ---- pl (col-marginal over m): in-lane over mt + 2-step ko butterfly;
    //      write epA cols 32..63. Keep plv for sm.
    float plv[2][4];
#pragma unroll
    for (int lt = 0; lt < 2; ++lt) {
#pragma unroll
        for (int reg = 0; reg < 4; ++reg) {
            float p = acc[0][lt][reg];
#pragma unroll
            for (int mt = 1; mt < 8; ++mt) p += acc[mt][lt][reg];
            p += __shfl_xor(p, 16, 64);
            p += __shfl_xor(p, 32, 64);
            plv[lt][reg] = p;
        }
        float w  = (ko & 1) ? plv[lt][1] : plv[lt][0];
        float w2 = (ko & 1) ? plv[lt][3] : plv[lt][2];
        float ww = (ko & 2) ? w2 : w;
        epA[(wv * 4 + ko) * PAD_K + 32 + lt * 16 + lc] = f2bf(ww);
    }

    // ---- sm[i] = sum_l pl[i][l] (pl replicated over ko): lt-fold + lc butterfly
    {
        float s[4];
#pragma unroll
        for (int reg = 0; reg < 4; ++reg) {
            float t = plv[0][reg] + plv[1][reg];
            t += __shfl_xor(t, 1, 64);
            t += __shfl_xor(t, 2, 64);
            t += __shfl_xor(t, 4, 64);
            t += __shfl_xor(t, 8, 64);
            s[reg] = t;
        }
        if (lane == 0) {
#pragma unroll
            for (int reg = 0; reg < 4; ++reg) sinv[wv * 4 + reg] = 1.0f / s[reg];
        }
    }

    // ---- pm via pair-tree reduction over lc: 30 shuffles, result distributed
    //      (lane bits encode (mt,reg)); write epA cols 0..31.
    {
        float v8[8][4];
#pragma unroll
        for (int mt = 0; mt < 8; ++mt)
#pragma unroll
            for (int reg = 0; reg < 4; ++reg)
                v8[mt][reg] = acc[mt][0][reg] + acc[mt][1][reg];

        const bool s0 = lane & 1, s1 = lane & 2, s2 = lane & 4, s3 = lane & 8;
        float r1[4][4];
#pragma unroll
        for (int m2 = 0; m2 < 4; ++m2)
#pragma unroll
            for (int reg = 0; reg < 4; ++reg) {
                float u = v8[2 * m2][reg], w = v8[2 * m2 + 1][reg];
                float a = s0 ? w : u;
                float s = s0 ? u : w;
                r1[m2][reg] = a + __shfl_xor(s, 1, 64);
            }
        float r2[2][4];
#pragma unroll
        for (int m4 = 0; m4 < 2; ++m4)
#pragma unroll
            for (int reg = 0; reg < 4; ++reg) {
                float u = r1[2 * m4][reg], w = r1[2 * m4 + 1][reg];
                float a = s1 ? w : u;
                float s = s1 ? u : w;
                r2[m4][reg] = a + __shfl_xor(s, 2, 64);
            }
        float r3[4];
#pragma unroll
        for (int reg = 0; reg < 4; ++reg) {
            float u = r2[0][reg], w = r2[1][reg];
            float a = s2 ? w : u;
            float s = s2 ? u : w;
            r3[reg] = a + __shfl_xor(s, 4, 64);
        }
        float a0 = s3 ? r3[1] : r3[0];
        float q0 = s3 ? r3[0] : r3[1];
        float g0 = a0 + __shfl_xor(q0, 8, 64);
        float a1 = s3 ? r3[3] : r3[2];
        float q1 = s3 ? r3[2] : r3[3];
        float g1 = a1 + __shfl_xor(q1, 8, 64);

        // lane(ko,lc): g0 -> pm[i = wv*4 + (lc>>3)][m = (lc&7)*4 + ko], g1 -> i+2
        int mcol = (lc & 7) * 4 + ko;
        int ib = wv * 4 + (lc >> 3);
        epA[ib * PAD_K + mcol]       = f2bf(g0);
        epA[(ib + 2) * PAD_K + mcol] = f2bf(g1);
    }

    // ---- epilogue B-frags from sd/se (pre-barrier; dd = wv*16+lc)
    const int dd = wv * 16 + lc;
    bf16x8 bd, be;
    {
        unsigned dv[8], ev[8];
#pragma unroll
        for (int j = 0; j < 8; ++j) {
            dv[j] = *reinterpret_cast<const unsigned short*>(&sd[(ko * 8 + j) * PAD_K + dd]);
            ev[j] = *reinterpret_cast<const unsigned short*>(&se[(ko * 8 + j) * PAD_K + dd]);
        }
        union { unsigned u[4]; bf16x8 v; } td, te;
#pragma unroll
        for (int j = 0; j < 4; ++j) {
            td.u[j] = __builtin_amdgcn_perm(dv[2 * j + 1], dv[2 * j], 0x05040100);
            te.u[j] = __builtin_amdgcn_perm(ev[2 * j + 1], ev[2 * j], 0x05040100);
        }
        bd = td.v; be = te.v;
    }
    __syncthreads();   // B2

    // ---- cooperative epilogue MFMA
    bf16x8 apm = *reinterpret_cast<const bf16x8*>(&epA[lc * PAD_K + ko * 8]);
    bf16x8 apl = *reinterpret_cast<const bf16x8*>(&epA[lc * PAD_K + 32 + ko * 8]);
    f32x4 zacc = (f32x4){0.f, 0.f, 0.f, 0.f};
    zacc = __builtin_amdgcn_mfma_f32_16x16x32_bf16(apm, bd, zacc, 0, 0, 0);
    zacc = __builtin_amdgcn_mfma_f32_16x16x32_bf16(apl, be, zacc, 0, 0, 0);

#pragma unroll
    for (int reg = 0; reg < 4; ++reg) {
        int i = ko * 4 + reg;
        z[((size_t)b * T_SEQ + nbase + i) * (NHEADS * DHEAD) + hd + dd] =
            f2bf(zacc[reg] * sinv[i]);
    }
}

// ---------------------------------------------------------------------------
extern "C" void kernel_launch(void* const* d_in, const int* in_sizes, int n_in,
                              void* d_out, int out_size, void* d_ws, size_t ws_size,
                              hipStream_t stream) {
    const float* x        = (const float*)d_in[0];
    const float* W_abcde  = (const float*)d_in[1];
    const float* b_abcde  = (const float*)d_in[2];
    const float* W_O      = (const float*)d_in[3];
    const float* b_O      = (const float*)d_in[4];
    float* out = (float*)d_out;

    char* ws = (char*)d_ws;
    short* abcde = (short*)ws;                                  // 4096x3840 bf16 (31.5 MB)
    short* xb    = (short*)(ws + (size_t)31457280);             // 4096x768 bf16, reused as zb
    short* Wt    = (short*)(ws + (size_t)31457280 + 6291456);   // 3840x768 bf16
    short* WOt   = (short*)(ws + (size_t)31457280 + 6291456 + 5898240); // 768x768 bf16
    short* zb    = xb;

    const int M = 2 * T_SEQ;  // 4096

    prep_kernel<<<dim3(4992), dim3(256), 0, stream>>>(
        x, W_abcde, W_O, xb, Wt, WOt);

    gemm_bf16_n64<true><<<dim3(NABCDE / 64, M / 128), dim3(256), 0, stream>>>(
        xb, Wt, b_abcde, (void*)abcde, M, NABCDE, DMODEL);

    attn_kernel<<<dim3(2 * NHEADS * NWIN), dim3(256), 0, stream>>>(abcde, zb);

    gemm_bf16_n64<false><<<dim3(DMODEL / 64, M / 128), dim3(256), 0, stream>>>(
        zb, WOt, b_O, (void*)out, M, DMODEL, DMODEL);
}